// Round 1
// baseline (132.965 us; speedup 1.0000x reference)
//
#include <hip/hip_runtime.h>
#include <hip/hip_bf16.h>

#define I_DIM 4096
#define J_DIM 4096
#define NPERM0 10
#define NPERM1 10
#define RROWS 4          // output rows per block
#define FUSED_THREADS 512

// soft mask: clip((xi-gamma)*sigmoid(x)+gamma, 0, 1) with xi=1.1, gamma=-0.1
__device__ __forceinline__ float soft_mask(float x) {
    float s = 1.0f / (1.0f + __expf(-x));
    return fminf(fmaxf(1.2f * s - 0.1f, 0.0f), 1.0f);
}

// Pass 0: sw = weight * soft_mask(sparse_mask), float4-vectorized.
__global__ __launch_bounds__(256) void sw_kernel(
    const float* __restrict__ w, const float* __restrict__ m,
    float* __restrict__ sw, int n4) {
    int idx = blockIdx.x * blockDim.x + threadIdx.x;
    if (idx >= n4) return;
    float4 wv = reinterpret_cast<const float4*>(w)[idx];
    float4 mv = reinterpret_cast<const float4*>(m)[idx];
    float4 o;
    o.x = wv.x * soft_mask(mv.x);
    o.y = wv.y * soft_mask(mv.y);
    o.z = wv.z * soft_mask(mv.z);
    o.w = wv.w * soft_mask(mv.w);
    reinterpret_cast<float4*>(sw)[idx] = o;
}

// Fused pass: per block, RROWS output rows.
//   Phase A (row-mix, commuted order): v[r][c] = sum_p ps0[p,i_r] * sw[perm0[p,i_r], c]
//     -> stored in LDS as [c][r] so one float4 spans the 4 rows of column c.
//   Phase B (col-mix): out[i_r][c] = sum_q v[r][perm1[q,c]] * ps1[q,c]
//     -> one ds_read_b128 per (q,c) yields all 4 rows.
__global__ __launch_bounds__(FUSED_THREADS) void fused_kernel(
    const float* __restrict__ sw,
    const float* __restrict__ ps0,   // (NPERM0, I)
    const float* __restrict__ ps1,   // (NPERM1, J)
    const int*   __restrict__ perm0, // (NPERM0, I)
    const int*   __restrict__ perm1, // (NPERM1, J)
    float* __restrict__ out) {
    __shared__ float vlds[J_DIM * RROWS];  // 64 KiB, layout [c][r]

    const int i0 = blockIdx.x * RROWS;

    // Hoist per-block uniform row indices / scales (wave-uniform -> scalar loads).
    int   row[NPERM0][RROWS];
    float sc [NPERM0][RROWS];
#pragma unroll
    for (int p = 0; p < NPERM0; ++p)
#pragma unroll
        for (int r = 0; r < RROWS; ++r) {
            row[p][r] = perm0[p * I_DIM + i0 + r];
            sc [p][r] = ps0 [p * I_DIM + i0 + r];
        }

    // Phase A: build v rows into LDS.
    for (int c = threadIdx.x; c < J_DIM; c += FUSED_THREADS) {
        float acc[RROWS] = {0.f, 0.f, 0.f, 0.f};
#pragma unroll
        for (int p = 0; p < NPERM0; ++p) {
#pragma unroll
            for (int r = 0; r < RROWS; ++r) {
                acc[r] += sc[p][r] * sw[(size_t)row[p][r] * J_DIM + c];
            }
        }
        float4 v4 = make_float4(acc[0], acc[1], acc[2], acc[3]);
        *reinterpret_cast<float4*>(&vlds[(size_t)c * RROWS]) = v4;  // contiguous b128, conflict-free
    }
    __syncthreads();

    // Phase B: column gather + combine, write out.
    for (int c = threadIdx.x; c < J_DIM; c += FUSED_THREADS) {
        float o[RROWS] = {0.f, 0.f, 0.f, 0.f};
#pragma unroll
        for (int q = 0; q < NPERM1; ++q) {
            int   pc = perm1[q * J_DIM + c];
            float s  = ps1 [q * J_DIM + c];
            float4 v = *reinterpret_cast<const float4*>(&vlds[(size_t)pc * RROWS]);
            o[0] += s * v.x;
            o[1] += s * v.y;
            o[2] += s * v.z;
            o[3] += s * v.w;
        }
#pragma unroll
        for (int r = 0; r < RROWS; ++r) {
            out[(size_t)(i0 + r) * J_DIM + c] = o[r];
        }
    }
}

extern "C" void kernel_launch(void* const* d_in, const int* in_sizes, int n_in,
                              void* d_out, int out_size, void* d_ws, size_t ws_size,
                              hipStream_t stream) {
    const float* weight = (const float*)d_in[0];
    const float* smask  = (const float*)d_in[1];
    const float* ps0    = (const float*)d_in[2];
    const float* ps1    = (const float*)d_in[3];
    const int*   perm0  = (const int*)d_in[4];
    const int*   perm1  = (const int*)d_in[5];
    float* out = (float*)d_out;
    float* sw  = (float*)d_ws;   // needs I*J*4 = 64 MiB scratch

    const int n4 = I_DIM * J_DIM / 4;
    sw_kernel<<<n4 / 256, 256, 0, stream>>>(weight, smask, sw, n4);
    fused_kernel<<<I_DIM / RROWS, FUSED_THREADS, 0, stream>>>(
        sw, ps0, ps1, perm0, perm1, out);
}